// Round 6
// baseline (405.672 us; speedup 1.0000x reference)
//
#include <hip/hip_runtime.h>

#pragma clang fp contract(off)

#define NA 131072
#define NC 8
#define NK 2048
#define NSORT 4096
#define SEG 256        // per-wave key segment (8192 anchors/wave, ~82 hits expected)
#define NW 32
#define CONF 0.99f
#define IMGW 320.0f
#define IMGH 256.0f

typedef unsigned long long u64;

// Exact-decision IoU > 0.5, usually division-free (verified absmax 0.0 in r4/r5):
// diff = inter - 0.5*uni decides; fall back to the correctly-rounded division
// only in the provable ambiguity band.
__device__ __forceinline__ bool iou_gt(float4 bi, float ai, float4 bj, float aj) {
    float xx1 = fmaxf(bi.x, bj.x), yy1 = fmaxf(bi.y, bj.y);
    float xx2 = fminf(bi.z, bj.z), yy2 = fminf(bi.w, bj.w);
    float inter = fmaxf(xx2 - xx1, 0.0f) * fmaxf(yy2 - yy1, 0.0f);
    float uni = (ai + aj) - inter;
    float th = 0.5f * uni;
    float diff = inter - th;
    bool pred = diff > 0.0f;
    if (__builtin_expect((uni < 1e-8f) || (pred && diff < th * 1e-6f), 0)) {
        pred = (inter / fmaxf(uni, 1e-8f)) > 0.5f;
    }
    return pred;
}

// Whole detector post-process in ONE kernel: one block (1024 thr) per class.
// Phases: scan/compact -> bitonic sort -> lazy decode -> intra masks ->
//         chunked bitmask greedy NMS -> output write. All state in LDS.
__global__ __launch_bounds__(1024) void k_all(const float* __restrict__ cls,
                                              const float4* __restrict__ reg,
                                              const float4* __restrict__ anc,
                                              float* __restrict__ out) {
    __shared__ u64 kv[NSORT];       // 32 KB  key = (score_bits<<32) | ~anchor
    __shared__ float4 bxs[NK];      // 32 KB  decoded boxes, sorted order
    __shared__ float bar[NK];       // 8 KB   areas
    __shared__ float ssc[NK];       // 8 KB   scores
    __shared__ u64 intra[NK];       // 16 KB  per-row in-chunk suppression word
    __shared__ u64 remv[NW];
    __shared__ u64 keptw[NW];
    __shared__ int wcnt_sh[16];

    int c = blockIdx.x;
    int tid = threadIdx.x;
    int lane = tid & 63;
    int wid = tid >> 6;

    // ---- phase 0+1: zero own kv segment, scan class column, compact ----
    for (int i = lane; i < SEG; i += 64) kv[wid * SEG + i] = 0ULL;
    int wcnt = 0;
    for (int it = 0; it < NA / 1024; ++it) {
        int a = it * 1024 + tid;
        float s = cls[(size_t)a * NC + c];
        bool p = s > CONF;
        u64 m = __ballot(p);
        if (p) {
            int pos = wcnt + (int)__popcll(m & ((1ULL << lane) - 1ULL));
            if (pos < SEG)
                kv[wid * SEG + pos] =
                    ((u64)__float_as_uint(s) << 32) | (unsigned)(~a);
        }
        wcnt += (int)__popcll(m);
    }
    if (lane == 0) wcnt_sh[wid] = min(wcnt, SEG);
    __syncthreads();

    int meff = 0;
    #pragma unroll
    for (int w = 0; w < 16; ++w) meff += wcnt_sh[w];
    meff = min(meff, NK);

    // ---- phase 2: bitonic sort, descending, NSORT elements ----
    // (zero pads sink; real keys are all positive)
    for (int k = 2; k <= NSORT; k <<= 1) {
        for (int j = k >> 1; j > 0; j >>= 1) {
            #pragma unroll
            for (int q = 0; q < NSORT / 1024; ++q) {
                int i = q * 1024 + tid;
                int l = i ^ j;
                if (l > i) {
                    u64 a = kv[i], b = kv[l];
                    bool desc = ((i & k) == 0);
                    if (desc ? (a < b) : (a > b)) { kv[i] = b; kv[l] = a; }
                }
            }
            __syncthreads();
        }
    }

    // ---- phase 3: lazy decode of the top meff boxes into sorted slots ----
    for (int r = tid; r < meff; r += 1024) {
        u64 ke = kv[r];
        int idx = (int)(~(unsigned)ke);
        float4 av = anc[idx];
        float4 rv = reg[idx];
        float wa = av.z - av.x, ha = av.w - av.y;
        float cxa = av.x + 0.5f * wa, cya = av.y + 0.5f * ha;
        float dx = rv.x * 0.1f, dy = rv.y * 0.1f;
        float dw = rv.z * 0.2f, dh = rv.w * 0.2f;
        float pcx = cxa + dx * wa, pcy = cya + dy * ha;
        float pw = expf(dw) * wa, ph = expf(dh) * ha;
        float4 b;
        b.x = fmaxf(pcx - 0.5f * pw, 0.0f);
        b.y = fmaxf(pcy - 0.5f * ph, 0.0f);
        b.z = fminf(pcx + 0.5f * pw, IMGW);
        b.w = fminf(pcy + 0.5f * ph, IMGH);
        bxs[r] = b;
        bar[r] = fmaxf(b.z - b.x, 0.0f) * fmaxf(b.w - b.y, 0.0f);
        ssc[r] = __uint_as_float((unsigned)(ke >> 32));
    }
    __syncthreads();

    // ---- phase 4: per-row intra-chunk suppression words (parallel) ----
    for (int r = wid; r < meff; r += 16) {
        float4 bi = bxs[r];
        float ai = bar[r];
        int col = (r & ~63) | lane;
        bool pred = (col > r) && (col < meff) &&
                    iou_gt(bi, ai, bxs[col], bar[col]);
        u64 m = __ballot(pred);
        if (lane == 0) intra[r] = m;
    }
    if (tid < NW) { remv[tid] = 0ULL; keptw[tid] = 0ULL; }
    __syncthreads();

    // ---- phase 5: chunked greedy (bitops serial + parallel forward apply) ----
    int nchunk = (meff + 63) >> 6;
    for (int t = 0; t < nchunk; ++t) {
        if (wid == 0) {
            int r = t * 64 + lane;
            bool valid = (r < meff) && !((remv[t] >> lane) & 1ULL);
            u64 pending = __ballot(valid);
            u64 mr = (r < meff) ? intra[r] : 0ULL;
            unsigned mlo = (unsigned)mr, mhi = (unsigned)(mr >> 32);
            u64 kept = 0ULL;
            while (pending) {
                int b = __ffsll(pending) - 1;
                kept |= 1ULL << b;
                unsigned lo = (unsigned)__builtin_amdgcn_readlane((int)mlo, b);
                unsigned hi = (unsigned)__builtin_amdgcn_readlane((int)mhi, b);
                pending &= ~((((u64)hi << 32) | lo) | (1ULL << b));
            }
            if (lane == 0) keptw[t] = kept;
        }
        __syncthreads();

        u64 kept = keptw[t];
        if (kept) {
            for (int wd = t + 1 + wid; wd < nchunk; wd += 16) {
                int col = wd * 64 + lane;
                bool alive = col < meff;
                float4 bj = make_float4(0, 0, 0, 0);
                float aj = 0;
                if (alive) { bj = bxs[col]; aj = bar[col]; }
                u64 acc = 0ULL;
                u64 bits = kept;
                while (bits) {
                    int b = __ffsll(bits) - 1;
                    bits &= bits - 1;
                    int r = t * 64 + b;
                    float4 bi = bxs[r];      // broadcast LDS reads
                    float ai = bar[r];
                    bool pred = alive && iou_gt(bi, ai, bj, aj);
                    acc |= __ballot(pred);
                }
                if (lane == 0 && acc) remv[wd] |= acc;
            }
        }
        __syncthreads();
    }

    // ---- phase 6: write all NK rows for this class ----
    for (int r = tid; r < NK; r += 1024) {
        bool kp = (r < meff) && ((keptw[r >> 6] >> (r & 63)) & 1ULL);
        float4 b = make_float4(0, 0, 0, 0);
        float s = 0.0f, cl = 0.0f;
        if (kp) { b = bxs[r]; s = ssc[r]; cl = (float)c; }
        int o = (c * NK + r) * 6;
        out[o + 0] = b.x;
        out[o + 1] = b.y;
        out[o + 2] = b.z;
        out[o + 3] = b.w;
        out[o + 4] = s;
        out[o + 5] = cl;
    }
}

extern "C" void kernel_launch(void* const* d_in, const int* in_sizes, int n_in,
                              void* d_out, int out_size, void* d_ws, size_t ws_size,
                              hipStream_t stream) {
    const float* cls = (const float*)d_in[0];   // [1, A, C]
    const float4* reg = (const float4*)d_in[1]; // [1, A, 4]
    const float4* anc = (const float4*)d_in[2]; // [1, A, 4]
    float* out = (float*)d_out;                 // [C*K, 6]

    k_all<<<NC, 1024, 0, stream>>>(cls, reg, anc, out);
}

// Round 8
// 367.720 us; speedup vs baseline: 1.1032x; 1.1032x over previous
//
#include <hip/hip_runtime.h>

#pragma clang fp contract(off)

#define NA 131072
#define NC 8
#define NK 2048
#define CAP 8192       // sort capacity (LDS kv), statistically unreachable (+190σ)
#define NW 32
#define CONF 0.99f
#define IMGW 320.0f
#define IMGH 256.0f
#define CSTRIDE 32     // ints between class counters (separate cachelines)

typedef unsigned long long u64;

// ---------------- ws layout (bytes) ----------------
// counts : NC*CSTRIDE int @ 0     (1 KB)
// vkey   : NC*CAP u64     @ 1024  (512 KB)

// Exact-decision IoU > 0.5, usually division-free (absmax 0.0 in r4/r5/r6):
// diff = inter - 0.5*uni decides; correctly-rounded division only in the
// provable ambiguity band.
__device__ __forceinline__ bool iou_gt(float4 bi, float ai, float4 bj, float aj) {
    float xx1 = fmaxf(bi.x, bj.x), yy1 = fmaxf(bi.y, bj.y);
    float xx2 = fminf(bi.z, bj.z), yy2 = fminf(bi.w, bj.w);
    float inter = fmaxf(xx2 - xx1, 0.0f) * fmaxf(yy2 - yy1, 0.0f);
    float uni = (ai + aj) - inter;
    float th = 0.5f * uni;
    float diff = inter - th;
    bool pred = diff > 0.0f;
    if (__builtin_expect((uni < 1e-8f) || (pred && diff < th * 1e-6f), 0)) {
        pred = (inter / fmaxf(uni, 1e-8f)) > 0.5f;
    }
    return pred;
}

__global__ void k_zero(int* __restrict__ counts) {
    counts[threadIdx.x] = 0;
}

// Parallel score scan + compaction (proven r5 structure): 128 blocks,
// coalesced float4 reads of all 8 class scores per anchor, per-block
// LDS-aggregated counts -> ONE global atomic per class per block.
// key = (score_bits << 32) | ~anchor  -> desc key == (score desc, idx asc)
__global__ __launch_bounds__(1024) void k_scan(const float* __restrict__ cls,
                                               int* __restrict__ counts,
                                               u64* __restrict__ vkey) {
    __shared__ int lcnt[NC];
    __shared__ int lbase[NC];
    int tid = threadIdx.x;
    int lane = tid & 63;
    int a = blockIdx.x * 1024 + tid;

    const float4* c4 = (const float4*)(cls + (size_t)a * NC);
    float4 s0 = c4[0], s1 = c4[1];
    float sc[8] = {s0.x, s0.y, s0.z, s0.w, s1.x, s1.y, s1.z, s1.w};

    if (tid < NC) lcnt[tid] = 0;
    __syncthreads();

    int wbase[NC], off[NC];
    bool hit[NC];
    #pragma unroll
    for (int c = 0; c < NC; ++c) {
        float s = sc[c];
        bool p = s > CONF;
        u64 m = __ballot(p);
        int cnt = __popcll(m);
        int wb = 0;
        if (cnt && lane == 0) wb = atomicAdd(&lcnt[c], cnt);
        wb = __shfl(wb, 0);
        wbase[c] = wb;
        hit[c] = p;
        off[c] = __popcll(m & ((1ULL << lane) - 1ULL));
    }
    __syncthreads();
    if (tid < NC) lbase[tid] = atomicAdd(&counts[tid * CSTRIDE], lcnt[tid]);
    __syncthreads();

    #pragma unroll
    for (int c = 0; c < NC; ++c) {
        if (hit[c]) {
            int pos = lbase[c] + wbase[c] + off[c];
            if (pos < CAP) {
                vkey[c * CAP + pos] =
                    ((u64)__float_as_uint(sc[c]) << 32) | (unsigned int)(~a);
            }
        }
    }
}

// Per-class fused: bitonic sort -> lazy decode -> intra masks -> bitmask
// greedy with on-the-fly forward suppression -> write. One block / class.
__global__ __launch_bounds__(1024) void k_nms(const int* __restrict__ counts,
                                              const u64* __restrict__ vkey,
                                              const float4* __restrict__ anc,
                                              const float4* __restrict__ reg,
                                              float* __restrict__ out) {
    __shared__ u64 kv[CAP];         // 64 KB
    __shared__ float4 bxs[NK];      // 32 KB
    __shared__ float bar[NK];       // 8 KB
    __shared__ float ssc[NK];       // 8 KB
    __shared__ u64 intra[NK];       // 16 KB
    __shared__ u64 remv[NW];
    __shared__ u64 keptw[NW];

    int c = blockIdx.x;
    int tid = threadIdx.x;
    int lane = tid & 63;
    int wid = tid >> 6;

    int M = min(counts[c * CSTRIDE], CAP);
    int meff = min(M, NK);

    // ---- stage keys, zero-pad to CAP (pads sink in descending sort) ----
    for (int i = tid; i < CAP; i += 1024)
        kv[i] = (i < M) ? vkey[c * CAP + i] : 0ULL;
    __syncthreads();

    // ---- bitonic sort, descending, CAP elements (pair-indexed) ----
    for (int k = 2; k <= CAP; k <<= 1) {
        for (int j = k >> 1; j > 0; j >>= 1) {
            #pragma unroll
            for (int q = 0; q < CAP / 2 / 1024; ++q) {
                int v = q * 1024 + tid;
                int i = ((v & ~(j - 1)) << 1) | (v & (j - 1));
                int l = i + j;
                bool desc = ((i & k) == 0);
                u64 a = kv[i], b = kv[l];
                if (desc ? (a < b) : (a > b)) { kv[i] = b; kv[l] = a; }
            }
            __syncthreads();
        }
    }

    // ---- lazy decode of top meff into sorted slots ----
    for (int r = tid; r < meff; r += 1024) {
        u64 ke = kv[r];
        int idx = (int)(~(unsigned)ke);
        float4 av = anc[idx];
        float4 rv = reg[idx];
        float wa = av.z - av.x, ha = av.w - av.y;
        float cxa = av.x + 0.5f * wa, cya = av.y + 0.5f * ha;
        float dx = rv.x * 0.1f, dy = rv.y * 0.1f;
        float dw = rv.z * 0.2f, dh = rv.w * 0.2f;
        float pcx = cxa + dx * wa, pcy = cya + dy * ha;
        float pw = expf(dw) * wa, ph = expf(dh) * ha;
        float4 b;
        b.x = fmaxf(pcx - 0.5f * pw, 0.0f);
        b.y = fmaxf(pcy - 0.5f * ph, 0.0f);
        b.z = fminf(pcx + 0.5f * pw, IMGW);
        b.w = fminf(pcy + 0.5f * ph, IMGH);
        bxs[r] = b;
        bar[r] = fmaxf(b.z - b.x, 0.0f) * fmaxf(b.w - b.y, 0.0f);
        ssc[r] = __uint_as_float((unsigned)(ke >> 32));
    }
    __syncthreads();

    // ---- per-row intra-chunk suppression words (parallel) ----
    for (int r = wid; r < meff; r += 16) {
        float4 bi = bxs[r];
        float ai = bar[r];
        int col = (r & ~63) | lane;
        bool pred = (col > r) && (col < meff) &&
                    iou_gt(bi, ai, bxs[col], bar[col]);
        u64 m = __ballot(pred);
        if (lane == 0) intra[r] = m;
    }
    if (tid < NW) { remv[tid] = 0ULL; keptw[tid] = 0ULL; }
    __syncthreads();

    // ---- chunked greedy: bitops serial + parallel forward apply ----
    int nchunk = (meff + 63) >> 6;
    for (int t = 0; t < nchunk; ++t) {
        if (wid == 0) {
            int r = t * 64 + lane;
            bool valid = (r < meff) && !((remv[t] >> lane) & 1ULL);
            u64 pending = __ballot(valid);
            u64 mr = (r < meff) ? intra[r] : 0ULL;
            unsigned mlo = (unsigned)mr, mhi = (unsigned)(mr >> 32);
            u64 kept = 0ULL;
            while (pending) {
                int b = __ffsll(pending) - 1;
                kept |= 1ULL << b;
                unsigned lo = (unsigned)__builtin_amdgcn_readlane((int)mlo, b);
                unsigned hi = (unsigned)__builtin_amdgcn_readlane((int)mhi, b);
                pending &= ~((((u64)hi << 32) | lo) | (1ULL << b));
            }
            if (lane == 0) keptw[t] = kept;
        }
        __syncthreads();

        u64 kept = keptw[t];
        if (kept) {
            for (int wd = t + 1 + wid; wd < nchunk; wd += 16) {
                int col = wd * 64 + lane;
                bool alive = col < meff;
                float4 bj = make_float4(0, 0, 0, 0);
                float aj = 0;
                if (alive) { bj = bxs[col]; aj = bar[col]; }
                u64 acc = 0ULL;
                u64 bits = kept;
                while (bits) {
                    int b = __ffsll(bits) - 1;
                    bits &= bits - 1;
                    int r = t * 64 + b;
                    float4 bi = bxs[r];      // broadcast LDS reads
                    float ai = bar[r];
                    bool pred = alive && iou_gt(bi, ai, bj, aj);
                    acc |= __ballot(pred);
                }
                if (lane == 0 && acc) remv[wd] |= acc;
            }
        }
        __syncthreads();
    }

    // ---- write all NK rows for this class ----
    for (int r = tid; r < NK; r += 1024) {
        bool kp = (r < meff) && ((keptw[r >> 6] >> (r & 63)) & 1ULL);
        float4 b = make_float4(0, 0, 0, 0);
        float s = 0.0f, cl = 0.0f;
        if (kp) { b = bxs[r]; s = ssc[r]; cl = (float)c; }
        int o = (c * NK + r) * 6;
        out[o + 0] = b.x;
        out[o + 1] = b.y;
        out[o + 2] = b.z;
        out[o + 3] = b.w;
        out[o + 4] = s;
        out[o + 5] = cl;
    }
}

extern "C" void kernel_launch(void* const* d_in, const int* in_sizes, int n_in,
                              void* d_out, int out_size, void* d_ws, size_t ws_size,
                              hipStream_t stream) {
    const float* cls = (const float*)d_in[0];   // [1, A, C]
    const float4* reg = (const float4*)d_in[1]; // [1, A, 4]
    const float4* anc = (const float4*)d_in[2]; // [1, A, 4]
    float* out = (float*)d_out;                 // [C*K, 6]

    char* ws = (char*)d_ws;
    int* counts = (int*)(ws + 0);
    u64* vkey = (u64*)(ws + 1024);

    k_zero<<<1, NC * CSTRIDE, 0, stream>>>(counts);
    k_scan<<<NA / 1024, 1024, 0, stream>>>(cls, counts, vkey);
    k_nms<<<NC, 1024, 0, stream>>>(counts, vkey, anc, reg, out);
}

// Round 9
// 314.818 us; speedup vs baseline: 1.2886x; 1.1680x over previous
//
#include <hip/hip_runtime.h>

#pragma clang fp contract(off)

#define NA 131072
#define NC 8
#define NK 2048
#define CAP 8192       // key capacity per class (statistically unreachable)
#define NW 32
#define NB 256         // rank buckets (164 used by the score range)
#define CONF 0.99f
#define IMGW 320.0f
#define IMGH 256.0f
#define CSTRIDE 32     // ints between class counters (separate cachelines)

typedef unsigned long long u64;

// ---------------- ws layout (bytes) ----------------
// counts : NC*CSTRIDE int @ 0     (1 KB)
// vkey   : NC*CAP u64     @ 1024  (512 KB)

// Monotonic bucket index: higher score -> lower bucket. Scores are in
// (0.99, 1.0), so bits(1.0)-bits(s) is in (0, 0x28F5C); >>10 gives 0..163.
__device__ __forceinline__ int bucket_of(unsigned sb) {
    int d = (int)(0x3F800000u - sb);
    return min(max(d >> 10, 0), NB - 1);
}

// Exact-decision IoU > 0.5, usually division-free (absmax 0.0 r4-r8):
// diff = inter - 0.5*uni decides; correctly-rounded division only in the
// provable ambiguity band.
__device__ __forceinline__ bool iou_gt(float4 bi, float ai, float4 bj, float aj) {
    float xx1 = fmaxf(bi.x, bj.x), yy1 = fmaxf(bi.y, bj.y);
    float xx2 = fminf(bi.z, bj.z), yy2 = fminf(bi.w, bj.w);
    float inter = fmaxf(xx2 - xx1, 0.0f) * fmaxf(yy2 - yy1, 0.0f);
    float uni = (ai + aj) - inter;
    float th = 0.5f * uni;
    float diff = inter - th;
    bool pred = diff > 0.0f;
    if (__builtin_expect((uni < 1e-8f) || (pred && diff < th * 1e-6f), 0)) {
        pred = (inter / fmaxf(uni, 1e-8f)) > 0.5f;
    }
    return pred;
}

__global__ void k_zero(int* __restrict__ counts) {
    counts[threadIdx.x] = 0;
}

// Parallel score scan + compaction (proven r5/r8 structure): 128 blocks,
// coalesced float4 reads, per-block LDS-aggregated counts -> ONE global
// atomic per class per block.
// key = (score_bits << 32) | ~anchor  -> desc key == (score desc, idx asc)
__global__ __launch_bounds__(1024) void k_scan(const float* __restrict__ cls,
                                               int* __restrict__ counts,
                                               u64* __restrict__ vkey) {
    __shared__ int lcnt[NC];
    __shared__ int lbase[NC];
    int tid = threadIdx.x;
    int lane = tid & 63;
    int a = blockIdx.x * 1024 + tid;

    const float4* c4 = (const float4*)(cls + (size_t)a * NC);
    float4 s0 = c4[0], s1 = c4[1];
    float sc[8] = {s0.x, s0.y, s0.z, s0.w, s1.x, s1.y, s1.z, s1.w};

    if (tid < NC) lcnt[tid] = 0;
    __syncthreads();

    int wbase[NC], off[NC];
    bool hit[NC];
    #pragma unroll
    for (int c = 0; c < NC; ++c) {
        float s = sc[c];
        bool p = s > CONF;
        u64 m = __ballot(p);
        int cnt = __popcll(m);
        int wb = 0;
        if (cnt && lane == 0) wb = atomicAdd(&lcnt[c], cnt);
        wb = __shfl(wb, 0);
        wbase[c] = wb;
        hit[c] = p;
        off[c] = __popcll(m & ((1ULL << lane) - 1ULL));
    }
    __syncthreads();
    if (tid < NC) lbase[tid] = atomicAdd(&counts[tid * CSTRIDE], lcnt[tid]);
    __syncthreads();

    #pragma unroll
    for (int c = 0; c < NC; ++c) {
        if (hit[c]) {
            int pos = lbase[c] + wbase[c] + off[c];
            if (pos < CAP) {
                vkey[c * CAP + pos] =
                    ((u64)__float_as_uint(sc[c]) << 32) | (unsigned int)(~a);
            }
        }
    }
}

// Per-class fused: O(M) counting-rank -> lazy decode -> intra masks ->
// bitmask greedy with on-the-fly forward suppression -> write.
__global__ __launch_bounds__(1024) void k_nms(const int* __restrict__ counts,
                                              const u64* __restrict__ vkey,
                                              const float4* __restrict__ anc,
                                              const float4* __restrict__ reg,
                                              float* __restrict__ out) {
    __shared__ u64 skv[CAP];        // 64 KB  bucket-segmented keys
    __shared__ float4 bxs[NK];      // 32 KB  boxes in rank order
    __shared__ float bar[NK];       // 8 KB
    __shared__ float ssc[NK];       // 8 KB
    __shared__ u64 intra[NK];       // 16 KB
    __shared__ int hist[NB];
    __shared__ int basep[NB];
    __shared__ int cnt[NB];
    __shared__ u64 remv[NW];
    __shared__ u64 keptw[NW];

    int c = blockIdx.x;
    int tid = threadIdx.x;
    int lane = tid & 63;
    int wid = tid >> 6;

    int M = min(counts[c * CSTRIDE], CAP);
    int meff = min(M, NK);

    // ---- phase 1: bucket histogram ----
    for (int i = tid; i < NB; i += 1024) { hist[i] = 0; cnt[i] = 0; }
    __syncthreads();
    for (int e = tid; e < M; e += 1024) {
        u64 ke = vkey[c * CAP + e];
        atomicAdd(&hist[bucket_of((unsigned)(ke >> 32))], 1);
    }
    __syncthreads();

    // ---- phase 2: exclusive prefix sum over buckets (wave 0) ----
    if (wid == 0) {
        int s0 = hist[4 * lane + 0], s1 = hist[4 * lane + 1];
        int s2 = hist[4 * lane + 2], s3 = hist[4 * lane + 3];
        int lsum = s0 + s1 + s2 + s3;
        int x = lsum;
        #pragma unroll
        for (int d = 1; d < 64; d <<= 1) {
            int y = __shfl_up(x, d);
            if (lane >= d) x += y;
        }
        int excl = x - lsum;
        basep[4 * lane + 0] = excl;
        basep[4 * lane + 1] = excl + s0;
        basep[4 * lane + 2] = excl + s0 + s1;
        basep[4 * lane + 3] = excl + s0 + s1 + s2;
    }
    __syncthreads();

    // ---- phase 3: scatter keys into bucket segments ----
    for (int e = tid; e < M; e += 1024) {
        u64 ke = vkey[c * CAP + e];
        int b = bucket_of((unsigned)(ke >> 32));
        int pos = basep[b] + atomicAdd(&cnt[b], 1);
        skv[pos] = ke;
    }
    __syncthreads();

    // ---- phase 4: exact rank (bucket base + #larger in bucket) + decode ----
    for (int p = tid; p < M; p += 1024) {
        u64 ke = skv[p];
        int b = bucket_of((unsigned)(ke >> 32));
        int st = basep[b], ln = hist[b];
        int rank = st;
        for (int q = st; q < st + ln; ++q) rank += (skv[q] > ke);
        if (rank < NK) {
            int idx = (int)(~(unsigned)ke);
            float4 av = anc[idx];
            float4 rv = reg[idx];
            float wa = av.z - av.x, ha = av.w - av.y;
            float cxa = av.x + 0.5f * wa, cya = av.y + 0.5f * ha;
            float dx = rv.x * 0.1f, dy = rv.y * 0.1f;
            float dw = rv.z * 0.2f, dh = rv.w * 0.2f;
            float pcx = cxa + dx * wa, pcy = cya + dy * ha;
            float pw = expf(dw) * wa, ph = expf(dh) * ha;
            float4 bb;
            bb.x = fmaxf(pcx - 0.5f * pw, 0.0f);
            bb.y = fmaxf(pcy - 0.5f * ph, 0.0f);
            bb.z = fminf(pcx + 0.5f * pw, IMGW);
            bb.w = fminf(pcy + 0.5f * ph, IMGH);
            bxs[rank] = bb;
            bar[rank] = fmaxf(bb.z - bb.x, 0.0f) * fmaxf(bb.w - bb.y, 0.0f);
            ssc[rank] = __uint_as_float((unsigned)(ke >> 32));
        }
    }
    __syncthreads();

    // ---- phase 5: per-row intra-chunk suppression words (parallel) ----
    for (int r = wid; r < meff; r += 16) {
        float4 bi = bxs[r];
        float ai = bar[r];
        int col = (r & ~63) | lane;
        bool pred = (col > r) && (col < meff) &&
                    iou_gt(bi, ai, bxs[col], bar[col]);
        u64 m = __ballot(pred);
        if (lane == 0) intra[r] = m;
    }
    if (tid < NW) { remv[tid] = 0ULL; keptw[tid] = 0ULL; }
    __syncthreads();

    // ---- phase 6: chunked greedy (bitops serial + parallel forward apply) ----
    int nchunk = (meff + 63) >> 6;
    for (int t = 0; t < nchunk; ++t) {
        if (wid == 0) {
            int r = t * 64 + lane;
            bool valid = (r < meff) && !((remv[t] >> lane) & 1ULL);
            u64 pending = __ballot(valid);
            u64 mr = (r < meff) ? intra[r] : 0ULL;
            unsigned mlo = (unsigned)mr, mhi = (unsigned)(mr >> 32);
            u64 kept = 0ULL;
            while (pending) {
                int b = __ffsll(pending) - 1;
                kept |= 1ULL << b;
                unsigned lo = (unsigned)__builtin_amdgcn_readlane((int)mlo, b);
                unsigned hi = (unsigned)__builtin_amdgcn_readlane((int)mhi, b);
                pending &= ~((((u64)hi << 32) | lo) | (1ULL << b));
            }
            if (lane == 0) keptw[t] = kept;
        }
        __syncthreads();

        u64 kept = keptw[t];
        if (kept) {
            for (int wd = t + 1 + wid; wd < nchunk; wd += 16) {
                int col = wd * 64 + lane;
                bool alive = col < meff;
                float4 bj = make_float4(0, 0, 0, 0);
                float aj = 0;
                if (alive) { bj = bxs[col]; aj = bar[col]; }
                u64 acc = 0ULL;
                u64 bits = kept;
                while (bits) {
                    int b = __ffsll(bits) - 1;
                    bits &= bits - 1;
                    int r = t * 64 + b;
                    float4 bi = bxs[r];      // broadcast LDS reads
                    float ai = bar[r];
                    bool pred = alive && iou_gt(bi, ai, bj, aj);
                    acc |= __ballot(pred);
                }
                if (lane == 0 && acc) remv[wd] |= acc;
            }
        }
        __syncthreads();
    }

    // ---- phase 7: write all NK rows for this class ----
    for (int r = tid; r < NK; r += 1024) {
        bool kp = (r < meff) && ((keptw[r >> 6] >> (r & 63)) & 1ULL);
        float4 b = make_float4(0, 0, 0, 0);
        float s = 0.0f, cl = 0.0f;
        if (kp) { b = bxs[r]; s = ssc[r]; cl = (float)c; }
        int o = (c * NK + r) * 6;
        out[o + 0] = b.x;
        out[o + 1] = b.y;
        out[o + 2] = b.z;
        out[o + 3] = b.w;
        out[o + 4] = s;
        out[o + 5] = cl;
    }
}

extern "C" void kernel_launch(void* const* d_in, const int* in_sizes, int n_in,
                              void* d_out, int out_size, void* d_ws, size_t ws_size,
                              hipStream_t stream) {
    const float* cls = (const float*)d_in[0];   // [1, A, C]
    const float4* reg = (const float4*)d_in[1]; // [1, A, 4]
    const float4* anc = (const float4*)d_in[2]; // [1, A, 4]
    float* out = (float*)d_out;                 // [C*K, 6]

    char* ws = (char*)d_ws;
    int* counts = (int*)(ws + 0);
    u64* vkey = (u64*)(ws + 1024);

    k_zero<<<1, NC * CSTRIDE, 0, stream>>>(counts);
    k_scan<<<NA / 1024, 1024, 0, stream>>>(cls, counts, vkey);
    k_nms<<<NC, 1024, 0, stream>>>(counts, vkey, anc, reg, out);
}